// Round 1
// baseline (435.435 us; speedup 1.0000x reference)
//
#include <hip/hip_runtime.h>

#define BATCH   8
#define HWDIM   1025
#define CELLS   (HWDIM * HWDIM)          // 1050625
#define TPB     256
#define CPT     4
#define CPB     (TPB * CPT)              // 1024 cells per block
#define NB      ((CELLS + CPB - 1) / CPB)  // 1027 blocks per (batch,table)
#define NCOUNT  (BATCH * 2 * NB)         // 16432 scan entries
#define OUT_ROWS (2 * BATCH * CELLS)     // 16810000 rows of float4

// Midpoint offset tables, precomputed from FIRST/SECOND x CORNERS.
// Row layout: [m01_y, m01_x, m23_y, m23_x] added to (y, x, y, x).
__constant__ float OFF1[16][4] = {
    { 0.0f,  0.0f,  0.0f,  0.0f},   // 0 (invalid)
    { 0.0f, -0.5f,  0.5f,  0.0f},   // 1
    { 0.5f,  0.0f,  0.0f,  0.5f},   // 2
    { 0.0f, -0.5f,  0.0f,  0.5f},   // 3
    { 0.0f,  0.5f, -0.5f,  0.0f},   // 4
    { 0.0f, -0.5f,  0.5f,  0.0f},   // 5
    { 0.5f,  0.0f, -0.5f,  0.0f},   // 6
    { 0.0f, -0.5f, -0.5f,  0.0f},   // 7
    {-0.5f,  0.0f,  0.0f, -0.5f},   // 8
    {-0.5f,  0.0f,  0.5f,  0.0f},   // 9
    { 0.5f,  0.0f,  0.0f,  0.5f},   // 10
    {-0.5f,  0.0f,  0.0f,  0.5f},   // 11
    { 0.0f,  0.5f,  0.0f, -0.5f},   // 12
    { 0.0f,  0.5f,  0.5f,  0.0f},   // 13
    { 0.5f,  0.0f,  0.0f, -0.5f},   // 14
    { 0.0f,  0.0f,  0.0f,  0.0f},   // 15 (invalid)
};
__constant__ float OFF2[2][4] = {
    { 0.0f,  0.5f, -0.5f,  0.0f},   // code 5
    {-0.5f,  0.0f,  0.0f, -0.5f},   // code 10
};

// corners for cell (y,x) of the padded grid map to clamped coarse indices
__device__ __forceinline__ int cell_code(const float* __restrict__ base, int y, int x) {
    int yt = (y > 0) ? y - 1 : 0;        // y-1 clamped (y-1 <= 1023 already)
    int yb = (y < 1024) ? y : 1023;      // y clamped
    int xl = (x > 0) ? x - 1 : 0;
    int xr = (x < 1024) ? x : 1023;
    float nw = base[yt * 1024 + xl];
    float ne = base[yt * 1024 + xr];
    float sw = base[yb * 1024 + xl];
    float se = base[yb * 1024 + xr];
    int code = 0;
    code |= (sw > 0.0f) ? 1 : 0;
    code |= (se > 0.0f) ? 2 : 0;
    code |= (ne > 0.0f) ? 4 : 0;
    code |= (nw > 0.0f) ? 8 : 0;
    return code;
}

// Pass 1: per-block valid counts, stored in key-enumeration order:
// index = b*2*NB + table*NB + blk
__global__ __launch_bounds__(TPB) void k_count(const float* __restrict__ coarse,
                                               int* __restrict__ counts) {
    int b   = blockIdx.x / NB;
    int blk = blockIdx.x % NB;
    const float* base = coarse + (size_t)b * 1024 * 1024;
    int t = threadIdx.x;
    int i0 = blk * CPB + t * CPT;

    int c1 = 0, c2 = 0;
#pragma unroll
    for (int k = 0; k < CPT; ++k) {
        int i = i0 + k;
        if (i < CELLS) {
            int y = i / HWDIM;
            int x = i - y * HWDIM;
            int code = cell_code(base, y, x);
            c1 += (code > 0 && code < 15) ? 1 : 0;
            c2 += (code == 5 || code == 10) ? 1 : 0;
        }
    }
    __shared__ int s1, s2;
    if (t == 0) { s1 = 0; s2 = 0; }
    __syncthreads();
#pragma unroll
    for (int off = 32; off > 0; off >>= 1) {
        c1 += __shfl_down(c1, off);
        c2 += __shfl_down(c2, off);
    }
    if ((t & 63) == 0) { atomicAdd(&s1, c1); atomicAdd(&s2, c2); }
    __syncthreads();
    if (t == 0) {
        counts[b * 2 * NB + blk]      = s1;
        counts[b * 2 * NB + NB + blk] = s2;
    }
}

// Pass 2: single-block exclusive scan of the 16432 counts.
// Also writes total T and the 8 per-batch counts (as float) to d_out tail.
__global__ __launch_bounds__(1024) void k_scan(const int* __restrict__ counts,
                                               int* __restrict__ offsets,
                                               int* __restrict__ totalp,
                                               float* __restrict__ out_counts) {
    __shared__ int sums[1024];
    int t = threadIdx.x;
    const int E = (NCOUNT + 1023) / 1024;   // 17
    int local[E];
    int s = 0;
#pragma unroll
    for (int k = 0; k < E; ++k) {
        int idx = t * E + k;
        int v = (idx < NCOUNT) ? counts[idx] : 0;
        local[k] = s;
        s += v;
    }
    sums[t] = s;
    __syncthreads();
    // Hillis-Steele inclusive scan over 1024 partials
    for (int off = 1; off < 1024; off <<= 1) {
        int v = (t >= off) ? sums[t - off] : 0;
        __syncthreads();
        sums[t] += v;
        __syncthreads();
    }
    int texcl = (t > 0) ? sums[t - 1] : 0;
#pragma unroll
    for (int k = 0; k < E; ++k) {
        int idx = t * E + k;
        if (idx < NCOUNT) offsets[idx] = texcl + local[k];
    }
    int T = sums[1023];
    if (t == 0) *totalp = T;
    __syncthreads();
    if (t < BATCH) {
        int start = offsets[t * 2 * NB];              // written above; block-visible after barrier
        int end   = (t == BATCH - 1) ? T : offsets[(t + 1) * 2 * NB];
        out_counts[t] = (float)(end - start);
    }
}

// Pass 3: emit. Every candidate slot (cell x table) writes exactly one float4:
// valid -> midpoints at its compacted rank; invalid -> zeros at
// T + (enum_pos - valid_prefix)  (a bijection onto the tail region).
__global__ __launch_bounds__(TPB) void k_emit(const float* __restrict__ coarse,
                                              const int* __restrict__ offsets,
                                              const int* __restrict__ totalp,
                                              float4* __restrict__ out) {
    int b   = blockIdx.x / NB;
    int blk = blockIdx.x % NB;
    const float* base = coarse + (size_t)b * 1024 * 1024;
    int t = threadIdx.x;
    int T = *totalp;
    int i0 = blk * CPB + t * CPT;

    int codes[CPT];
    int ys[CPT], xs[CPT];
    bool live[CPT];
    int n1 = 0, n2 = 0;
#pragma unroll
    for (int k = 0; k < CPT; ++k) {
        int i = i0 + k;
        live[k] = (i < CELLS);
        int code = 0, y = 0, x = 0;
        if (live[k]) {
            y = i / HWDIM;
            x = i - y * HWDIM;
            code = cell_code(base, y, x);
        }
        codes[k] = code; ys[k] = y; xs[k] = x;
        n1 += (live[k] && code > 0 && code < 15) ? 1 : 0;
        n2 += (live[k] && (code == 5 || code == 10)) ? 1 : 0;
    }

    // in-order block scan of (n1, n2) packed as n1 | n2<<16
    __shared__ int ssc[TPB];
    ssc[t] = n1 | (n2 << 16);
    __syncthreads();
    for (int off = 1; off < TPB; off <<= 1) {
        int v = (t >= off) ? ssc[t - off] : 0;
        __syncthreads();
        ssc[t] += v;
        __syncthreads();
    }
    int incl = ssc[t];
    int p1 = (incl & 0xffff) - n1;   // exclusive prefix, table 1
    int p2 = (incl >> 16) - n2;      // exclusive prefix, table 2

    int off1b = offsets[b * 2 * NB + blk];
    int off2b = offsets[b * 2 * NB + NB + blk];

    // table-1 slots
    int vc = 0;
#pragma unroll
    for (int k = 0; k < CPT; ++k) {
        if (!live[k]) continue;
        int i = i0 + k;
        int code = codes[k];
        bool v = (code > 0 && code < 15);
        int vpref = off1b + p1 + vc;                 // #valid slots before this one
        int gp = (2 * b) * CELLS + i;                // key-enumeration position
        int row = v ? vpref : (T + gp - vpref);
        float4 val;
        if (v) {
            const float* o = OFF1[code];
            val = make_float4((float)ys[k] + o[0], (float)xs[k] + o[1],
                              (float)ys[k] + o[2], (float)xs[k] + o[3]);
        } else {
            val = make_float4(0.f, 0.f, 0.f, 0.f);
        }
        out[(size_t)row] = val;
        vc += v ? 1 : 0;
    }
    // table-2 slots
    vc = 0;
#pragma unroll
    for (int k = 0; k < CPT; ++k) {
        if (!live[k]) continue;
        int i = i0 + k;
        int code = codes[k];
        bool v = (code == 5 || code == 10);
        int vpref = off2b + p2 + vc;
        int gp = (2 * b + 1) * CELLS + i;
        int row = v ? vpref : (T + gp - vpref);
        float4 val;
        if (v) {
            const float* o = OFF2[(code == 10) ? 1 : 0];
            val = make_float4((float)ys[k] + o[0], (float)xs[k] + o[1],
                              (float)ys[k] + o[2], (float)xs[k] + o[3]);
        } else {
            val = make_float4(0.f, 0.f, 0.f, 0.f);
        }
        out[(size_t)row] = val;
        vc += v ? 1 : 0;
    }
}

extern "C" void kernel_launch(void* const* d_in, const int* in_sizes, int n_in,
                              void* d_out, int out_size, void* d_ws, size_t ws_size,
                              hipStream_t stream) {
    const float* coarse = (const float*)d_in[0];
    float* out = (float*)d_out;
    int* wsi = (int*)d_ws;
    int* counts  = wsi;                 // NCOUNT ints
    int* offsets = wsi + NCOUNT;        // NCOUNT ints
    int* totalp  = wsi + 2 * NCOUNT;    // 1 int

    k_count<<<dim3(BATCH * NB), dim3(TPB), 0, stream>>>(coarse, counts);
    k_scan<<<dim3(1), dim3(1024), 0, stream>>>(counts, offsets, totalp,
                                               out + (size_t)OUT_ROWS * 4);
    k_emit<<<dim3(BATCH * NB), dim3(TPB), 0, stream>>>(coarse, offsets, totalp,
                                                       (float4*)out);
}

// Round 2
// 329.145 us; speedup vs baseline: 1.3229x; 1.3229x over previous
//
#include <hip/hip_runtime.h>

#define BATCH   8
#define HWDIM   1025
#define CELLS   (HWDIM * HWDIM)          // 1050625
#define TPB     256
#define CPT     4
#define CPB     (TPB * CPT)              // 1024 cells per block
#define NB      ((CELLS + CPB - 1) / CPB)  // 1027 blocks per (batch,table)
#define NCOUNT  (BATCH * 2 * NB)         // 16432 scan entries
#define OUT_ROWS (2 * BATCH * CELLS)     // 16810000 rows of float4

// Midpoint offset tables, precomputed from FIRST/SECOND x CORNERS.
// Row layout: [m01_y, m01_x, m23_y, m23_x] added to (y, x, y, x).
__constant__ float OFF1[16][4] = {
    { 0.0f,  0.0f,  0.0f,  0.0f},   // 0 (invalid)
    { 0.0f, -0.5f,  0.5f,  0.0f},   // 1
    { 0.5f,  0.0f,  0.0f,  0.5f},   // 2
    { 0.0f, -0.5f,  0.0f,  0.5f},   // 3
    { 0.0f,  0.5f, -0.5f,  0.0f},   // 4
    { 0.0f, -0.5f,  0.5f,  0.0f},   // 5
    { 0.5f,  0.0f, -0.5f,  0.0f},   // 6
    { 0.0f, -0.5f, -0.5f,  0.0f},   // 7
    {-0.5f,  0.0f,  0.0f, -0.5f},   // 8
    {-0.5f,  0.0f,  0.5f,  0.0f},   // 9
    { 0.5f,  0.0f,  0.0f,  0.5f},   // 10
    {-0.5f,  0.0f,  0.0f,  0.5f},   // 11
    { 0.0f,  0.5f,  0.0f, -0.5f},   // 12
    { 0.0f,  0.5f,  0.5f,  0.0f},   // 13
    { 0.5f,  0.0f,  0.0f, -0.5f},   // 14
    { 0.0f,  0.0f,  0.0f,  0.0f},   // 15 (invalid)
};
__constant__ float OFF2[2][4] = {
    { 0.0f,  0.5f, -0.5f,  0.0f},   // code 5
    {-0.5f,  0.0f,  0.0f, -0.5f},   // code 10
};

// corners for cell (y,x) of the padded grid map to clamped coarse indices
__device__ __forceinline__ int cell_code(const float* __restrict__ base, int y, int x) {
    int yt = (y > 0) ? y - 1 : 0;
    int yb = (y < 1024) ? y : 1023;
    int xl = (x > 0) ? x - 1 : 0;
    int xr = (x < 1024) ? x : 1023;
    float nw = base[yt * 1024 + xl];
    float ne = base[yt * 1024 + xr];
    float sw = base[yb * 1024 + xl];
    float se = base[yb * 1024 + xr];
    int code = 0;
    code |= (sw > 0.0f) ? 1 : 0;
    code |= (se > 0.0f) ? 2 : 0;
    code |= (ne > 0.0f) ? 4 : 0;
    code |= (nw > 0.0f) ? 8 : 0;
    return code;
}

// Pass 1: per-block valid counts in key-enumeration order:
// index = b*2*NB + table*NB + blk.  Stride-TPB layout -> coalesced reads.
__global__ __launch_bounds__(TPB) void k_count(const float* __restrict__ coarse,
                                               int* __restrict__ counts) {
    int b   = blockIdx.x / NB;
    int blk = blockIdx.x % NB;
    const float* base = coarse + (size_t)b * 1024 * 1024;
    int t = threadIdx.x;
    int lane = t & 63;

    int c1 = 0, c2 = 0;
#pragma unroll
    for (int k = 0; k < CPT; ++k) {
        int i = blk * CPB + k * TPB + t;
        if (i < CELLS) {
            int y = i / HWDIM;
            int x = i - y * HWDIM;
            int code = cell_code(base, y, x);
            c1 += (code > 0 && code < 15) ? 1 : 0;
            c2 += (code == 5 || code == 10) ? 1 : 0;
        }
    }
    __shared__ int s1, s2;
    if (t == 0) { s1 = 0; s2 = 0; }
    __syncthreads();
#pragma unroll
    for (int off = 32; off > 0; off >>= 1) {
        c1 += __shfl_down(c1, off);
        c2 += __shfl_down(c2, off);
    }
    if (lane == 0) { atomicAdd(&s1, c1); atomicAdd(&s2, c2); }
    __syncthreads();
    if (t == 0) {
        counts[b * 2 * NB + blk]      = s1;
        counts[b * 2 * NB + NB + blk] = s2;
    }
}

// Pass 2: single-block exclusive scan of the 16432 counts.
// Also writes total T and the 8 per-batch counts (as float) to d_out tail.
__global__ __launch_bounds__(1024) void k_scan(const int* __restrict__ counts,
                                               int* __restrict__ offsets,
                                               int* __restrict__ totalp,
                                               float* __restrict__ out_counts) {
    __shared__ int sums[1024];
    int t = threadIdx.x;
    const int E = (NCOUNT + 1023) / 1024;   // 17
    int local[E];
    int s = 0;
#pragma unroll
    for (int k = 0; k < E; ++k) {
        int idx = t * E + k;
        int v = (idx < NCOUNT) ? counts[idx] : 0;
        local[k] = s;
        s += v;
    }
    sums[t] = s;
    __syncthreads();
    for (int off = 1; off < 1024; off <<= 1) {
        int v = (t >= off) ? sums[t - off] : 0;
        __syncthreads();
        sums[t] += v;
        __syncthreads();
    }
    int texcl = (t > 0) ? sums[t - 1] : 0;
#pragma unroll
    for (int k = 0; k < E; ++k) {
        int idx = t * E + k;
        if (idx < NCOUNT) offsets[idx] = texcl + local[k];
    }
    int T = sums[1023];
    if (t == 0) *totalp = T;
    __syncthreads();
    if (t < BATCH) {
        int start = offsets[t * 2 * NB];
        int end   = (t == BATCH - 1) ? T : offsets[(t + 1) * 2 * NB];
        out_counts[t] = (float)(end - start);
    }
}

// Pass 3: emit valid rows only, ballot-ranked so lanes write dense
// consecutive rows (fully coalesced).  Enumeration order inside the block
// is k-major then t, matching the counts above (same cell set per block).
__global__ __launch_bounds__(TPB) void k_emit(const float* __restrict__ coarse,
                                              const int* __restrict__ offsets,
                                              float4* __restrict__ out) {
    int b   = blockIdx.x / NB;
    int blk = blockIdx.x % NB;
    const float* base = coarse + (size_t)b * 1024 * 1024;
    int t = threadIdx.x;
    int wave = t >> 6, lane = t & 63;
    unsigned long long ltmask = (1ULL << lane) - 1ULL;

    __shared__ int ws1[CPT][4], ws2[CPT][4];
    int run1 = offsets[b * 2 * NB + blk];
    int run2 = offsets[b * 2 * NB + NB + blk];

#pragma unroll
    for (int k = 0; k < CPT; ++k) {
        int i = blk * CPB + k * TPB + t;
        bool live = (i < CELLS);
        int code = 0, y = 0, x = 0;
        if (live) {
            y = i / HWDIM;
            x = i - y * HWDIM;
            code = cell_code(base, y, x);
        }
        bool v1 = live && (code > 0 && code < 15);
        bool v2 = live && (code == 5 || code == 10);
        unsigned long long m1 = __ballot(v1);
        unsigned long long m2 = __ballot(v2);
        if (lane == 0) {
            ws1[k][wave] = __popcll(m1);
            ws2[k][wave] = __popcll(m2);
        }
        __syncthreads();
        int w1 = 0, w2 = 0;
#pragma unroll
        for (int w = 0; w < 4; ++w) {
            if (w < wave) { w1 += ws1[k][w]; w2 += ws2[k][w]; }
        }
        if (v1) {
            int r = run1 + w1 + __popcll(m1 & ltmask);
            const float* o = OFF1[code];
            out[(size_t)r] = make_float4((float)y + o[0], (float)x + o[1],
                                         (float)y + o[2], (float)x + o[3]);
        }
        if (v2) {
            int r = run2 + w2 + __popcll(m2 & ltmask);
            const float* o = OFF2[(code == 10) ? 1 : 0];
            out[(size_t)r] = make_float4((float)y + o[0], (float)x + o[1],
                                         (float)y + o[2], (float)x + o[3]);
        }
        // advance running totals (computed identically by all threads)
        run1 += ws1[k][0] + ws1[k][1] + ws1[k][2] + ws1[k][3];
        run2 += ws2[k][0] + ws2[k][1] + ws2[k][2] + ws2[k][3];
    }
}

// Pass 4: zero the tail [T, OUT_ROWS) with dense float4 stores.
__global__ __launch_bounds__(TPB) void k_zero(const int* __restrict__ totalp,
                                              float4* __restrict__ out) {
    int T = *totalp;
    int n = OUT_ROWS - T;
    int stride = gridDim.x * blockDim.x;
    float4 z = make_float4(0.f, 0.f, 0.f, 0.f);
    for (int j = blockIdx.x * blockDim.x + threadIdx.x; j < n; j += stride)
        out[(size_t)(T + j)] = z;
}

extern "C" void kernel_launch(void* const* d_in, const int* in_sizes, int n_in,
                              void* d_out, int out_size, void* d_ws, size_t ws_size,
                              hipStream_t stream) {
    const float* coarse = (const float*)d_in[0];
    float* out = (float*)d_out;
    int* wsi = (int*)d_ws;
    int* counts  = wsi;                 // NCOUNT ints
    int* offsets = wsi + NCOUNT;        // NCOUNT ints
    int* totalp  = wsi + 2 * NCOUNT;    // 1 int

    k_count<<<dim3(BATCH * NB), dim3(TPB), 0, stream>>>(coarse, counts);
    k_scan<<<dim3(1), dim3(1024), 0, stream>>>(counts, offsets, totalp,
                                               out + (size_t)OUT_ROWS * 4);
    k_emit<<<dim3(BATCH * NB), dim3(TPB), 0, stream>>>(coarse, offsets,
                                                       (float4*)out);
    k_zero<<<dim3(2048), dim3(TPB), 0, stream>>>(totalp, (float4*)out);
}

// Round 5
// 325.026 us; speedup vs baseline: 1.3397x; 1.0127x over previous
//
#include <hip/hip_runtime.h>

#define BATCH   8
#define HWDIM   1025
#define CELLS   (HWDIM * HWDIM)            // 1050625
#define TPB     256
#define CPT     4
#define CPB     (TPB * CPT)                // 1024 cells per block
#define NB      ((CELLS + CPB - 1) / CPB)  // 1027 blocks per (batch,table)
#define CPAD    (NB * CPB)                 // 1051648 (256-aligned per-batch code stride)
#define NCOUNT  (BATCH * 2 * NB)           // 16432 scan entries
#define OUT_ROWS (2 * BATCH * CELLS)       // 16810000 rows of float4
#define CODES_BYTES ((size_t)BATCH * CPAD) // 8413184
#define ZGRID   8192                       // tail-zero blocks fused into emit grid

// Midpoint offset tables, precomputed from FIRST/SECOND x CORNERS.
// Row layout: [m01_y, m01_x, m23_y, m23_x] added to (y, x, y, x).
__constant__ float OFF1[16][4] = {
    { 0.0f,  0.0f,  0.0f,  0.0f},   // 0 (invalid)
    { 0.0f, -0.5f,  0.5f,  0.0f},   // 1
    { 0.5f,  0.0f,  0.0f,  0.5f},   // 2
    { 0.0f, -0.5f,  0.0f,  0.5f},   // 3
    { 0.0f,  0.5f, -0.5f,  0.0f},   // 4
    { 0.0f, -0.5f,  0.5f,  0.0f},   // 5
    { 0.5f,  0.0f, -0.5f,  0.0f},   // 6
    { 0.0f, -0.5f, -0.5f,  0.0f},   // 7
    {-0.5f,  0.0f,  0.0f, -0.5f},   // 8
    {-0.5f,  0.0f,  0.5f,  0.0f},   // 9
    { 0.5f,  0.0f,  0.0f,  0.5f},   // 10
    {-0.5f,  0.0f,  0.0f,  0.5f},   // 11
    { 0.0f,  0.5f,  0.0f, -0.5f},   // 12
    { 0.0f,  0.5f,  0.5f,  0.0f},   // 13
    { 0.5f,  0.0f,  0.0f, -0.5f},   // 14
    { 0.0f,  0.0f,  0.0f,  0.0f},   // 15 (invalid)
};
__constant__ float OFF2[2][4] = {
    { 0.0f,  0.5f, -0.5f,  0.0f},   // code 5
    {-0.5f,  0.0f,  0.0f, -0.5f},   // code 10
};

__device__ __forceinline__ int cell_code(const float* __restrict__ base, int y, int x) {
    int yt = (y > 0) ? y - 1 : 0;
    int yb = (y < 1024) ? y : 1023;
    int xl = (x > 0) ? x - 1 : 0;
    int xr = (x < 1024) ? x : 1023;
    float nw = base[yt * 1024 + xl];
    float ne = base[yt * 1024 + xr];
    float sw = base[yb * 1024 + xl];
    float se = base[yb * 1024 + xr];
    int code = 0;
    code |= (sw > 0.0f) ? 1 : 0;
    code |= (se > 0.0f) ? 2 : 0;
    code |= (ne > 0.0f) ? 4 : 0;
    code |= (nw > 0.0f) ? 8 : 0;
    return code;
}

// Pass 1: compute codes once; persist 1 byte/cell; per-block valid counts in
// key-enumeration order: index = b*2*NB + table*NB + blk.
__global__ __launch_bounds__(TPB) void k_pass1(const float* __restrict__ coarse,
                                               unsigned char* __restrict__ codes,
                                               int* __restrict__ counts) {
    int b   = blockIdx.x / NB;
    int blk = blockIdx.x % NB;
    const float* base = coarse + (size_t)b * 1024 * 1024;
    unsigned char* cb = codes + (size_t)b * CPAD;
    int t = threadIdx.x;
    int lane = t & 63;

    __shared__ int s1, s2;
    if (t == 0) { s1 = 0; s2 = 0; }
    __syncthreads();

    int c1 = 0, c2 = 0;
#pragma unroll
    for (int k = 0; k < CPT; ++k) {
        int i = blk * CPB + k * TPB + t;
        int code = 0;
        if (i < CELLS) {
            int y = i / HWDIM;
            int x = i - y * HWDIM;
            code = cell_code(base, y, x);
        }
        cb[i] = (unsigned char)code;
        c1 += __popcll(__ballot(code > 0 && code < 15));
        c2 += __popcll(__ballot(code == 5 || code == 10));
    }
    if (lane == 0) { atomicAdd(&s1, c1); atomicAdd(&s2, c2); }
    __syncthreads();
    if (t == 0) {
        counts[b * 2 * NB + blk]      = s1;
        counts[b * 2 * NB + NB + blk] = s2;
    }
}

// Pass 2: single-block exclusive scan of the 16432 counts.
// Also writes total T and the 8 per-batch counts (as float) to d_out tail.
__global__ __launch_bounds__(1024) void k_scan(const int* __restrict__ counts,
                                               int* __restrict__ offsets,
                                               int* __restrict__ totalp,
                                               float* __restrict__ out_counts) {
    __shared__ int sums[1024];
    int t = threadIdx.x;
    const int E = (NCOUNT + 1023) / 1024;   // 17
    int local[E];
    int s = 0;
#pragma unroll
    for (int k = 0; k < E; ++k) {
        int idx = t * E + k;
        int v = (idx < NCOUNT) ? counts[idx] : 0;
        local[k] = s;
        s += v;
    }
    sums[t] = s;
    __syncthreads();
    for (int off = 1; off < 1024; off <<= 1) {
        int v = (t >= off) ? sums[t - off] : 0;
        __syncthreads();
        sums[t] += v;
        __syncthreads();
    }
    int texcl = (t > 0) ? sums[t - 1] : 0;
#pragma unroll
    for (int k = 0; k < E; ++k) {
        int idx = t * E + k;
        if (idx < NCOUNT) offsets[idx] = texcl + local[k];
    }
    int T = sums[1023];
    if (t == 0) *totalp = T;
    __syncthreads();
    if (t < BATCH) {
        int start = offsets[t * 2 * NB];
        int end   = (t == BATCH - 1) ? T : offsets[(t + 1) * 2 * NB];
        out_counts[t] = (float)(end - start);
    }
}

// Pass 3: emit valid rows from stored codes (ballot-ranked, dense coalesced
// writes) + fused tail zero-fill (blocks >= BATCH*NB).
__global__ __launch_bounds__(TPB) void k_emit(const unsigned char* __restrict__ codes,
                                              const int* __restrict__ offsets,
                                              const int* __restrict__ totalp,
                                              float4* __restrict__ out) {
    int t = threadIdx.x;

    if (blockIdx.x >= BATCH * NB) {
        // tail zero-fill: rows [T, OUT_ROWS), dense float4 stores
        int T = *totalp;
        int n = OUT_ROWS - T;
        int j = (blockIdx.x - BATCH * NB) * TPB + t;
        int stride = ZGRID * TPB;
        float4 z = make_float4(0.f, 0.f, 0.f, 0.f);
        for (; j < n; j += stride) out[(size_t)(T + j)] = z;
        return;
    }

    int b   = blockIdx.x / NB;
    int blk = blockIdx.x % NB;
    const unsigned char* cb = codes + (size_t)b * CPAD;
    int wave = t >> 6, lane = t & 63;
    unsigned long long ltmask = (1ULL << lane) - 1ULL;

    __shared__ int ws1[CPT][4], ws2[CPT][4];

    int code4[CPT];
    unsigned long long m1[CPT], m2[CPT];
#pragma unroll
    for (int k = 0; k < CPT; ++k) {
        int i = blk * CPB + k * TPB + t;
        int code = cb[i];
        code4[k] = code;
        m1[k] = __ballot(code > 0 && code < 15);
        m2[k] = __ballot(code == 5 || code == 10);
        if (lane == 0) {
            ws1[k][wave] = __popcll(m1[k]);
            ws2[k][wave] = __popcll(m2[k]);
        }
    }
    __syncthreads();

    int run1 = offsets[b * 2 * NB + blk];
    int run2 = offsets[b * 2 * NB + NB + blk];

#pragma unroll
    for (int k = 0; k < CPT; ++k) {
        int i = blk * CPB + k * TPB + t;
        int code = code4[k];
        int w1 = 0, w2 = 0;
#pragma unroll
        for (int w = 0; w < 4; ++w) {
            if (w < wave) { w1 += ws1[k][w]; w2 += ws2[k][w]; }
        }
        bool v1 = (code > 0 && code < 15);
        bool v2 = (code == 5 || code == 10);
        if (v1 || v2) {
            int y = i / HWDIM;
            int x = i - y * HWDIM;
            if (v1) {
                int r = run1 + w1 + __popcll(m1[k] & ltmask);
                const float* o = OFF1[code];
                out[(size_t)r] = make_float4((float)y + o[0], (float)x + o[1],
                                             (float)y + o[2], (float)x + o[3]);
            }
            if (v2) {
                int r = run2 + w2 + __popcll(m2[k] & ltmask);
                const float* o = OFF2[(code == 10) ? 1 : 0];
                out[(size_t)r] = make_float4((float)y + o[0], (float)x + o[1],
                                             (float)y + o[2], (float)x + o[3]);
            }
        }
        run1 += ws1[k][0] + ws1[k][1] + ws1[k][2] + ws1[k][3];
        run2 += ws2[k][0] + ws2[k][1] + ws2[k][2] + ws2[k][3];
    }
}

extern "C" void kernel_launch(void* const* d_in, const int* in_sizes, int n_in,
                              void* d_out, int out_size, void* d_ws, size_t ws_size,
                              hipStream_t stream) {
    const float* coarse = (const float*)d_in[0];
    float* out = (float*)d_out;
    unsigned char* codes = (unsigned char*)d_ws;
    int* counts  = (int*)(codes + CODES_BYTES);   // NCOUNT ints
    int* offsets = counts + NCOUNT;               // NCOUNT ints
    int* totalp  = offsets + NCOUNT;              // 1 int

    k_pass1<<<dim3(BATCH * NB), dim3(TPB), 0, stream>>>(coarse, codes, counts);
    k_scan<<<dim3(1), dim3(1024), 0, stream>>>(counts, offsets, totalp,
                                               out + (size_t)OUT_ROWS * 4);
    k_emit<<<dim3(BATCH * NB + ZGRID), dim3(TPB), 0, stream>>>(codes, offsets,
                                                               totalp,
                                                               (float4*)out);
}